// Round 15
// baseline (1829.708 us; speedup 1.0000x reference)
//
#include <hip/hip_runtime.h>
#include <hip/hip_bf16.h>

namespace {

constexpr int BB = 16;
constexpr int NN = 4096;
constexpr int MM = 1024;

using f32x4  = __attribute__((ext_vector_type(4))) float;
using bf16x8 = __attribute__((ext_vector_type(8))) short;

__device__ __forceinline__ float actf(float x, int act) {
    if (act == 1) return fmaxf(x, 0.f);
    if (act == 2) return x >= 0.f ? x : 0.2f * x;
    return x;
}

__device__ __forceinline__ ushort f2bf(float x) {
    __hip_bfloat16 h = __float2bfloat16(x);
    return *reinterpret_cast<ushort*>(&h);
}

// pack x as (hi_bf16 | lo_bf16<<16); x == hi + lo to ~2^-18 relative
__device__ __forceinline__ uint hilo_pack(float x) {
    ushort h = f2bf(x);
    float hf = __uint_as_float(((uint)h) << 16);
    ushort l = f2bf(x - hf);
    return (uint)h | ((uint)l << 16);
}

// 8 packed dwords -> hi bf16x8, lo bf16x8
__device__ __forceinline__ void split8(const uint* d, bf16x8& hi, bf16x8& lo) {
    union { uint u[4]; bf16x8 v; } H, L;
#pragma unroll
    for (int j = 0; j < 4; ++j) {
        H.u[j] = (d[2 * j] & 0xffffu) | (d[2 * j + 1] << 16);
        L.u[j] = (d[2 * j] >> 16) | (d[2 * j + 1] & 0xffff0000u);
    }
    hi = H.v; lo = L.v;
}

// ---------------------------------------------------------------------------
// MFMA pointwise-conv, split-precision bf16 (hi/lo, 3 MFMA ~ fp32 accuracy).
// NEW: optional input-side GN fold (scale/shift/act applied during staging,
// from gn_stats output) and optional bf16-transposed side output Yt[B][L][64]
// (valid only for 64-output convs, gridDim.y==1).
// ---------------------------------------------------------------------------
__global__ __launch_bounds__(256)
void conv_mfma(const float* __restrict__ X, int C, long x_bs,
               const float* __restrict__ W,
               const float* __restrict__ X2, long x2_bs,
               const float* __restrict__ W2,
               const float* __restrict__ bias,
               const float* __restrict__ gnw, const float* __restrict__ gnb,
               const float* __restrict__ gstats, int cpg, int act,
               float* __restrict__ Y, long y_bs, int L,
               ushort* __restrict__ Yt)
{
    __shared__ uint Wp[64 * 33];
    __shared__ uint Xp[128 * 33];
    __shared__ float scs[512], shs[512];
    const int t  = threadIdx.x;
    const int b  = blockIdx.z;
    const int o0 = blockIdx.y * 64;
    const int l0 = blockIdx.x * 128;
    const int w  = t >> 6;
    const int ln = t & 15;
    const int lq = (t >> 4) & 3;
    const int wo = (w & 1) * 32;
    const int wl = (w >> 1) * 64;
    const int sl  = t & 127;
    const int sch = (t >> 7) * 16;

    if (gnw) {
        for (int c = t; c < C; c += 256) {
            int sidx = (b * (C / cpg) + c / cpg) * 2;
            float mu = gstats[sidx], rs = gstats[sidx + 1];
            float sc = rs * gnw[c];
            scs[c] = sc;
            shs[c] = gnb[c] - mu * sc;
        }
    }

    f32x4 acc[2][4];
#pragma unroll
    for (int i = 0; i < 2; ++i)
#pragma unroll
        for (int j = 0; j < 4; ++j) acc[i][j] = (f32x4){0.f, 0.f, 0.f, 0.f};

    for (int c0 = 0; c0 < C; c0 += 32) {
        __syncthreads();   // also makes scs visible on first iteration
#pragma unroll
        for (int i = 0; i < 2; ++i) {
            int f = i * 256 + t;
            int r = f >> 3, q4 = (f & 7) * 4;
            float4 wv = *reinterpret_cast<const float4*>(&W[(long)(o0 + r) * C + c0 + q4]);
            Wp[r * 33 + q4 + 0] = hilo_pack(wv.x);
            Wp[r * 33 + q4 + 1] = hilo_pack(wv.y);
            Wp[r * 33 + q4 + 2] = hilo_pack(wv.z);
            Wp[r * 33 + q4 + 3] = hilo_pack(wv.w);
        }
        {
            const float* xc = X + (long)b * x_bs + (long)(c0 + sch) * L + l0 + sl;
            float scr[16], shr[16];
            if (gnw) {
#pragma unroll
                for (int c = 0; c < 16; ++c) {
                    scr[c] = scs[c0 + sch + c];
                    shr[c] = shs[c0 + sch + c];
                }
            }
            uint tmp[16];
#pragma unroll
            for (int c = 0; c < 16; ++c) {
                float xv = xc[(long)c * L];
                if (gnw) xv = actf(xv * scr[c] + shr[c], act);
                tmp[c] = hilo_pack(xv);
            }
#pragma unroll
            for (int c4 = 0; c4 < 4; ++c4) {
                uint4 v = make_uint4(tmp[c4 * 4], tmp[c4 * 4 + 1],
                                     tmp[c4 * 4 + 2], tmp[c4 * 4 + 3]);
                *reinterpret_cast<uint4*>(&Xp[sl * 33 + sch + c4 * 4]) = v;
            }
        }
        __syncthreads();

        bf16x8 ahi[2], alo[2];
#pragma unroll
        for (int ot = 0; ot < 2; ++ot) {
            uint d[8];
            *reinterpret_cast<uint4*>(d) =
                *reinterpret_cast<const uint4*>(&Wp[(wo + ot * 16 + ln) * 33 + lq * 8]);
            *reinterpret_cast<uint4*>(d + 4) =
                *reinterpret_cast<const uint4*>(&Wp[(wo + ot * 16 + ln) * 33 + lq * 8 + 4]);
            split8(d, ahi[ot], alo[ot]);
        }
#pragma unroll
        for (int lt = 0; lt < 4; ++lt) {
            uint d[8];
            *reinterpret_cast<uint4*>(d) =
                *reinterpret_cast<const uint4*>(&Xp[(wl + lt * 16 + ln) * 33 + lq * 8]);
            *reinterpret_cast<uint4*>(d + 4) =
                *reinterpret_cast<const uint4*>(&Xp[(wl + lt * 16 + ln) * 33 + lq * 8 + 4]);
            bf16x8 bhi, blo;
            split8(d, bhi, blo);
#pragma unroll
            for (int ot = 0; ot < 2; ++ot) {
                acc[ot][lt] = __builtin_amdgcn_mfma_f32_16x16x32_bf16(alo[ot], bhi, acc[ot][lt], 0, 0, 0);
                acc[ot][lt] = __builtin_amdgcn_mfma_f32_16x16x32_bf16(ahi[ot], blo, acc[ot][lt], 0, 0, 0);
                acc[ot][lt] = __builtin_amdgcn_mfma_f32_16x16x32_bf16(ahi[ot], bhi, acc[ot][lt], 0, 0, 0);
            }
        }
    }

    float x2v[4][3];
    if (X2) {
#pragma unroll
        for (int lt = 0; lt < 4; ++lt) {
            const int l = l0 + wl + lt * 16 + ln;
#pragma unroll
            for (int c = 0; c < 3; ++c)
                x2v[lt][c] = X2[(long)b * x2_bs + (long)c * L + l];
        }
    }
#pragma unroll
    for (int ot = 0; ot < 2; ++ot) {
        float bb4[4], w20[4], w21[4], w22[4];
#pragma unroll
        for (int r = 0; r < 4; ++r) {
            const int o = o0 + wo + ot * 16 + lq * 4 + r;
            bb4[r] = bias ? bias[o] : 0.f;
            if (X2) {
                w20[r] = W2[o * 3 + 0];
                w21[r] = W2[o * 3 + 1];
                w22[r] = W2[o * 3 + 2];
            }
        }
#pragma unroll
        for (int lt = 0; lt < 4; ++lt) {
            const int l = l0 + wl + lt * 16 + ln;
            float fv[4];
#pragma unroll
            for (int r = 0; r < 4; ++r) {
                float val = acc[ot][lt][r] + bb4[r];
                if (X2)
                    val += w20[r] * x2v[lt][0] + w21[r] * x2v[lt][1] + w22[r] * x2v[lt][2];
                fv[r] = val;
                Y[(long)b * y_bs + (long)(o0 + wo + ot * 16 + lq * 4 + r) * L + l] = val;
            }
            if (Yt) {   // bf16 transposed side output (only for 64-out convs)
                ushort4 o4 = make_ushort4(f2bf(fv[0]), f2bf(fv[1]), f2bf(fv[2]), f2bf(fv[3]));
                *reinterpret_cast<ushort4*>(
                    &Yt[((long)b * L + l) * 64 + wo + ot * 16 + lq * 4]) = o4;
            }
        }
    }
}

// ---------------------------------------------------------------------------
// Old fp32 conv (kept only for conv1, C=6)
// ---------------------------------------------------------------------------
__global__ __launch_bounds__(256)
void conv_gemm(const float* __restrict__ X1, int C1, long x1_bs,
               const float* __restrict__ W1,
               const float* __restrict__ X2, int C2, long x2_bs,
               const float* __restrict__ W2,
               const float* __restrict__ bias,
               float* __restrict__ Y, long y_bs, int L)
{
    __shared__ float Wt[64][17];
    __shared__ float Xt[16][128];
    const int t  = threadIdx.x;
    const int b  = blockIdx.z;
    const int o0 = blockIdx.y * 64;
    const int l0 = blockIdx.x * 128;
    const int ty = t >> 4, tx = t & 15;

    float acc[4][8];
#pragma unroll
    for (int i = 0; i < 4; ++i)
#pragma unroll
        for (int j = 0; j < 8; ++j) acc[i][j] = 0.f;

    for (int pass = 0; pass < 2; ++pass) {
        const float* X = pass ? X2 : X1;
        const float* W = pass ? W2 : W1;
        const int    C = pass ? C2 : C1;
        const long xbs = pass ? x2_bs : x1_bs;
        if (C <= 0 || X == nullptr) continue;
        for (int c0 = 0; c0 < C; c0 += 16) {
            __syncthreads();
#pragma unroll
            for (int i = 0; i < 4; ++i) {
                int flat = i * 256 + t;
                int oo = flat >> 4, kk = flat & 15;
                Wt[oo][kk] = (c0 + kk < C) ? W[(long)(o0 + oo) * C + c0 + kk] : 0.f;
            }
#pragma unroll
            for (int i = 0; i < 2; ++i) {
                int f4 = i * 256 + t;
                int kk = f4 >> 5, c4 = f4 & 31;
                float4 xv = make_float4(0.f, 0.f, 0.f, 0.f);
                if (c0 + kk < C)
                    xv = *reinterpret_cast<const float4*>(
                        X + (long)b * xbs + (long)(c0 + kk) * L + l0 + c4 * 4);
                *reinterpret_cast<float4*>(&Xt[kk][c4 * 4]) = xv;
            }
            __syncthreads();
#pragma unroll
            for (int kk = 0; kk < 16; ++kk) {
                float wv[4];
#pragma unroll
                for (int i = 0; i < 4; ++i) wv[i] = Wt[ty * 4 + i][kk];
                float4 xa = *reinterpret_cast<const float4*>(&Xt[kk][tx * 8]);
                float4 xb = *reinterpret_cast<const float4*>(&Xt[kk][tx * 8 + 4]);
                float xv[8] = {xa.x, xa.y, xa.z, xa.w, xb.x, xb.y, xb.z, xb.w};
#pragma unroll
                for (int i = 0; i < 4; ++i)
#pragma unroll
                    for (int j = 0; j < 8; ++j) acc[i][j] += wv[i] * xv[j];
            }
        }
    }

#pragma unroll
    for (int i = 0; i < 4; ++i) {
        const int oo = o0 + ty * 4 + i;
        const float bv = bias ? bias[oo] : 0.f;
        float* yp = Y + (long)b * y_bs + (long)oo * L + l0 + tx * 8;
        float4 v0 = make_float4(acc[i][0] + bv, acc[i][1] + bv, acc[i][2] + bv, acc[i][3] + bv);
        float4 v1 = make_float4(acc[i][4] + bv, acc[i][5] + bv, acc[i][6] + bv, acc[i][7] + bv);
        *reinterpret_cast<float4*>(yp)     = v0;
        *reinterpret_cast<float4*>(yp + 4) = v1;
    }
}

// ---------------------------------------------------------------------------
// GroupNorm stats / apply (apply kept only for the residual t-chain)
// ---------------------------------------------------------------------------
__global__ __launch_bounds__(256)
void gn_stats(const float* __restrict__ Y, long y_bs, int cpg, int L, int G,
              float* __restrict__ stats)
{
    const int bg = blockIdx.x;
    const int b = bg / G, g = bg - b * G;
    const float* p = Y + (long)b * y_bs + (long)g * cpg * L;
    const long cnt = (long)cpg * L;
    float s = 0.f, ss = 0.f;
    for (long i = (long)threadIdx.x * 4; i < cnt; i += 256 * 4) {
        float4 v = *reinterpret_cast<const float4*>(p + i);
        s  += v.x + v.y + v.z + v.w;
        ss += v.x * v.x + v.y * v.y + v.z * v.z + v.w * v.w;
    }
    __shared__ float rs[256], rss[256];
    rs[threadIdx.x] = s; rss[threadIdx.x] = ss;
    __syncthreads();
    for (int st = 128; st > 0; st >>= 1) {
        if (threadIdx.x < st) {
            rs[threadIdx.x]  += rs[threadIdx.x + st];
            rss[threadIdx.x] += rss[threadIdx.x + st];
        }
        __syncthreads();
    }
    if (threadIdx.x == 0) {
        float mu  = rs[0] / (float)cnt;
        float var = rss[0] / (float)cnt - mu * mu;
        stats[bg * 2]     = mu;
        stats[bg * 2 + 1] = rsqrtf(var + 1e-5f);
    }
}

__global__ __launch_bounds__(256)
void gn_apply(const float* __restrict__ src, long s_bs,
              float* __restrict__ dst, long d_bs,
              const float* __restrict__ res, long r_bs,
              const float* __restrict__ w, const float* __restrict__ bb,
              const float* __restrict__ stats,
              int C, int cpg, int L, int act)
{
    const long total4 = (long)BB * C * L / 4;
    const int G = C / cpg;
    for (long i4 = (long)blockIdx.x * 256 + threadIdx.x; i4 < total4;
         i4 += (long)gridDim.x * 256) {
        long flat = i4 * 4;
        int b = (int)(flat / ((long)C * L));
        long rem = flat - (long)b * C * L;
        int c = (int)(rem / L);
        long li = rem - (long)c * L;
        int sidx = (b * G + c / cpg) * 2;
        float mu = stats[sidx], rsig = stats[sidx + 1];
        float sc = rsig * w[c];
        float sh = bb[c] - mu * sc;
        float4 vv = *reinterpret_cast<const float4*>(src + (long)b * s_bs + (long)c * L + li);
        float4 ov;
        ov.x = actf(vv.x * sc + sh, act);
        ov.y = actf(vv.y * sc + sh, act);
        ov.z = actf(vv.z * sc + sh, act);
        ov.w = actf(vv.w * sc + sh, act);
        if (res) {
            float4 rv = *reinterpret_cast<const float4*>(res + (long)b * r_bs + (long)c * L + li);
            ov.x += rv.x; ov.y += rv.y; ov.z += rv.z; ov.w += rv.w;
        }
        *reinterpret_cast<float4*>(dst + (long)b * d_bs + (long)c * L + li) = ov;
    }
}

// ---------------------------------------------------------------------------
// MFMA attention phase 0 (unchanged from round 14)
// ---------------------------------------------------------------------------
__global__ __launch_bounds__(256)
void attn_stats_mfma(const ushort* __restrict__ qt, const ushort* __restrict__ kt,
                     float* __restrict__ rowmax, float* __restrict__ rowinv,
                     float* __restrict__ csp)
{
    __shared__ float red[16][5];
    __shared__ float rs_mx[16], rs_inv[16];

    const int t  = threadIdx.x;
    const int b  = blockIdx.y;
    const int n0 = blockIdx.x * 16;
    const int w  = t >> 6;
    const int ln = t & 15;
    const int lq = (t >> 4) & 3;

    const ushort* qtb = qt + ((long)b * NN + n0) * 64;
    const ushort* ktb = kt + (long)b * MM * 64;

    bf16x8 aq[2];
#pragma unroll
    for (int ks = 0; ks < 2; ++ks)
        aq[ks] = *reinterpret_cast<const bf16x8*>(qtb + (long)ln * 64 + ks * 32 + lq * 8);

    f32x4 sc[16];
#pragma unroll
    for (int ib = 0; ib < 4; ++ib) {
        bf16x8 bk[4][2];
#pragma unroll
        for (int ii = 0; ii < 4; ++ii) {
            const int m0 = (w * 16 + ib * 4 + ii) * 16;
#pragma unroll
            for (int ks = 0; ks < 2; ++ks)
                bk[ii][ks] = *reinterpret_cast<const bf16x8*>(
                    ktb + (long)(m0 + ln) * 64 + ks * 32 + lq * 8);
        }
#pragma unroll
        for (int ii = 0; ii < 4; ++ii) {
            f32x4 acc = {0.f, 0.f, 0.f, 0.f};
            acc = __builtin_amdgcn_mfma_f32_16x16x32_bf16(aq[0], bk[ii][0], acc, 0, 0, 0);
            acc = __builtin_amdgcn_mfma_f32_16x16x32_bf16(aq[1], bk[ii][1], acc, 0, 0, 0);
            sc[ib * 4 + ii] = acc;
        }
    }

    float m4[4];
#pragma unroll
    for (int r = 0; r < 4; ++r) {
        float mx = sc[0][r];
#pragma unroll
        for (int i = 1; i < 16; ++i) mx = fmaxf(mx, sc[i][r]);
#pragma unroll
        for (int off = 1; off <= 8; off <<= 1) mx = fmaxf(mx, __shfl_xor(mx, off, 64));
        m4[r] = mx;
    }
    if (ln == 0)
#pragma unroll
        for (int r = 0; r < 4; ++r) red[lq * 4 + r][w] = m4[r];
    __syncthreads();
    if (t < 16) {
        float mx = fmaxf(fmaxf(red[t][0], red[t][1]), fmaxf(red[t][2], red[t][3]));
        rs_mx[t] = mx;
        rowmax[(long)b * NN + n0 + t] = mx;
    }
    __syncthreads();

    float mxr[4], s4[4];
#pragma unroll
    for (int r = 0; r < 4; ++r) { mxr[r] = rs_mx[lq * 4 + r]; s4[r] = 0.f; }
#pragma unroll
    for (int i = 0; i < 16; ++i)
#pragma unroll
        for (int r = 0; r < 4; ++r) {
            float e = __expf(sc[i][r] - mxr[r]);
            sc[i][r] = e;
            s4[r] += e;
        }
#pragma unroll
    for (int r = 0; r < 4; ++r)
#pragma unroll
        for (int off = 1; off <= 8; off <<= 1) s4[r] += __shfl_xor(s4[r], off, 64);
    if (ln == 0)
#pragma unroll
        for (int r = 0; r < 4; ++r) red[lq * 4 + r][w] = s4[r];
    __syncthreads();
    if (t < 16) {
        float es = red[t][0] + red[t][1] + red[t][2] + red[t][3];
        float inv = 1.0f / es;
        rs_inv[t] = inv;
        rowinv[(long)b * NN + n0 + t] = inv;
    }
    __syncthreads();

    float riv[4];
#pragma unroll
    for (int r = 0; r < 4; ++r) riv[r] = rs_inv[lq * 4 + r];
    const long cbase = ((long)b * (NN / 16) + blockIdx.x) * MM;
#pragma unroll
    for (int i = 0; i < 16; ++i) {
        float c = sc[i][0] * riv[0] + sc[i][1] * riv[1] + sc[i][2] * riv[2] + sc[i][3] * riv[3];
        c += __shfl_xor(c, 16, 64);
        c += __shfl_xor(c, 32, 64);
        if (lq == 0) csp[cbase + (w * 16 + i) * 16 + ln] = c;
    }
}

// ---------------------------------------------------------------------------
// MFMA attention phase 1: 32 q-rows, chunked QK^T->PV; NEW: V fragments
// prefetched into registers before the QK^T MFMAs (latency overlap).
// ---------------------------------------------------------------------------
__global__ __launch_bounds__(256)
void attn_pv_mfma(const ushort* __restrict__ qt, const ushort* __restrict__ kt,
                  const ushort* __restrict__ vb,
                  const float* __restrict__ rowmax, const float* __restrict__ rowinv,
                  const float* __restrict__ qg, float* __restrict__ ug)
{
    __shared__ ushort Pb[2][32 * 256];   // 32 KB double-buffered P chunks

    const int t  = threadIdx.x;
    const int b  = blockIdx.y;
    const int n0 = blockIdx.x * 32;
    const int w  = t >> 6;
    const int rt = w & 1;
    const int ms = w >> 1;
    const int ln = t & 15;
    const int lq = (t >> 4) & 3;
    const int d0 = w * 16;

    const ushort* qtb = qt + ((long)b * NN + n0 + rt * 16) * 64;
    const ushort* ktb = kt + (long)b * MM * 64;
    const ushort* vbb = vb + (long)b * 64 * MM;

    float mx[4], ri[4];
#pragma unroll
    for (int r = 0; r < 4; ++r) {
        mx[r] = rowmax[(long)b * NN + n0 + rt * 16 + lq * 4 + r];
        ri[r] = rowinv[(long)b * NN + n0 + rt * 16 + lq * 4 + r];
    }

    bf16x8 aq[2];
#pragma unroll
    for (int ks = 0; ks < 2; ++ks)
        aq[ks] = *reinterpret_cast<const bf16x8*>(qtb + (long)ln * 64 + ks * 32 + lq * 8);

    f32x4 acc2[2];
    acc2[0] = (f32x4){0.f, 0.f, 0.f, 0.f};
    acc2[1] = (f32x4){0.f, 0.f, 0.f, 0.f};

    const int swz = (ln & 7) << 3;

    for (int c = 0; c < 4; ++c) {
        // batched K-fragment loads (16 in flight)
        bf16x8 bk[8][2];
#pragma unroll
        for (int it = 0; it < 8; ++it) {
            const int m = c * 256 + ms * 128 + it * 16 + ln;
#pragma unroll
            for (int ks = 0; ks < 2; ++ks)
                bk[it][ks] = *reinterpret_cast<const bf16x8*>(
                    ktb + (long)m * 64 + ks * 32 + lq * 8);
        }
        // prefetch V fragments for this chunk's PV (independent of LDS)
        bf16x8 av[8];
#pragma unroll
        for (int ks = 0; ks < 8; ++ks)
            av[ks] = *reinterpret_cast<const bf16x8*>(
                vbb + (long)(d0 + ln) * MM + c * 256 + ks * 32 + lq * 8);

        // QK^T + P-chunk write
        ushort* pc = &Pb[c & 1][0];
#pragma unroll
        for (int it = 0; it < 8; ++it) {
            f32x4 acc = {0.f, 0.f, 0.f, 0.f};
            acc = __builtin_amdgcn_mfma_f32_16x16x32_bf16(aq[0], bk[it][0], acc, 0, 0, 0);
            acc = __builtin_amdgcn_mfma_f32_16x16x32_bf16(aq[1], bk[it][1], acc, 0, 0, 0);
            const int mc = ms * 128 + it * 16 + ln;
#pragma unroll
            for (int r = 0; r < 4; ++r) {
                const int n = rt * 16 + lq * 4 + r;
                float p = __expf(acc[r] - mx[r]) * ri[r];
                pc[n * 256 + (mc ^ ((n & 7) << 3))] = f2bf(p);
            }
        }
        __syncthreads();
        // PV over this chunk
#pragma unroll
        for (int ks = 0; ks < 8; ++ks) {
            const int mo = ks * 32 + lq * 8;
#pragma unroll
            for (int nt = 0; nt < 2; ++nt) {
                bf16x8 bp = *reinterpret_cast<const bf16x8*>(
                    &pc[(nt * 16 + ln) * 256 + (mo ^ swz)]);
                acc2[nt] = __builtin_amdgcn_mfma_f32_16x16x32_bf16(av[ks], bp, acc2[nt], 0, 0, 0);
            }
        }
    }

    const long qb = (long)b * 64 * NN;
#pragma unroll
    for (int nt = 0; nt < 2; ++nt)
#pragma unroll
        for (int r = 0; r < 4; ++r) {
            const int dd = d0 + lq * 4 + r;
            const long idx = qb + (long)dd * NN + n0 + nt * 16 + ln;
            ug[idx] = qg[idx] - acc2[nt][r];
        }
}

__global__ __launch_bounds__(256)
void colsum_reduce(const float* __restrict__ csp, float* __restrict__ cs, int NT)
{
    int idx = blockIdx.x * 256 + threadIdx.x;   // over B*M
    int b = idx / MM, m = idx - b * MM;
    const float* p = csp + (long)b * NT * MM + m;
    float s = 0.f;
    for (int i = 0; i < NT; ++i) s += p[(long)i * MM];
    cs[idx] = s;
}

__global__ __launch_bounds__(256)
void vscale_cvt(const float* __restrict__ v, const float* __restrict__ cs,
                ushort* __restrict__ vb)
{
    long i4 = (long)blockIdx.x * 256 + threadIdx.x;
    long flat = i4 * 4;                          // index into [B][64][M]
    int b = (int)(flat / (64L * MM));
    int m = (int)(flat % MM);
    float4 vv = *reinterpret_cast<const float4*>(v + flat);
    float4 cv = *reinterpret_cast<const float4*>(cs + (long)b * MM + m);
    ushort4 o;
    o.x = f2bf(vv.x / (1e-9f + cv.x));
    o.y = f2bf(vv.y / (1e-9f + cv.y));
    o.z = f2bf(vv.z / (1e-9f + cv.z));
    o.w = f2bf(vv.w / (1e-9f + cv.w));
    *reinterpret_cast<ushort4*>(vb + flat) = o;
}

// ---------------------------------------------------------------------------
// Final GN4 + relu + transpose (unchanged)
// ---------------------------------------------------------------------------
__global__ __launch_bounds__(256)
void gn_out_transpose(const float* __restrict__ s2,
                      const float* __restrict__ w, const float* __restrict__ bb,
                      const float* __restrict__ stats,
                      float* __restrict__ out)
{
    __shared__ float ls[128 * 65];
    const int t = threadIdx.x;
    const int b = blockIdx.y;
    const int n0 = blockIdx.x * 64;
#pragma unroll
    for (int i = 0; i < 8; ++i) {
        int f4 = i * 256 + t;
        int o = f4 >> 4, c4 = f4 & 15;
        float4 vv = *reinterpret_cast<const float4*>(
            s2 + (long)b * 128 * NN + (long)o * NN + n0 + c4 * 4);
        int sidx = (b * 4 + (o >> 5)) * 2;
        float mu = stats[sidx], rsig = stats[sidx + 1];
        float sc = rsig * w[o], sh = bb[o] - mu * sc;
        ls[o * 65 + c4 * 4 + 0] = fmaxf(vv.x * sc + sh, 0.f);
        ls[o * 65 + c4 * 4 + 1] = fmaxf(vv.y * sc + sh, 0.f);
        ls[o * 65 + c4 * 4 + 2] = fmaxf(vv.z * sc + sh, 0.f);
        ls[o * 65 + c4 * 4 + 3] = fmaxf(vv.w * sc + sh, 0.f);
    }
    __syncthreads();
#pragma unroll
    for (int i = 0; i < 8; ++i) {
        int f4 = i * 256 + t;
        int nn = f4 >> 5, o4 = f4 & 31;
        float4 ov;
        ov.x = ls[(o4 * 4 + 0) * 65 + nn];
        ov.y = ls[(o4 * 4 + 1) * 65 + nn];
        ov.z = ls[(o4 * 4 + 2) * 65 + nn];
        ov.w = ls[(o4 * 4 + 3) * 65 + nn];
        *reinterpret_cast<float4*>(out + (long)b * NN * 128 + (long)(n0 + nn) * 128 + o4 * 4) = ov;
    }
}

} // namespace

extern "C" void kernel_launch(void* const* d_in, const int* in_sizes, int n_in,
                              void* d_out, int out_size, void* d_ws, size_t ws_size,
                              hipStream_t stream)
{
    (void)in_sizes; (void)n_in; (void)out_size; (void)ws_size;

    const float* x         = (const float*)d_in[0];
    const float* x_global  = (const float*)d_in[1];
    const float* xyz       = (const float*)d_in[2];
    const float* xyz_g     = (const float*)d_in[3];
    const float* conv1_w   = (const float*)d_in[4];
    const float* gn1_w     = (const float*)d_in[5];
    const float* gn1_b     = (const float*)d_in[6];
    const float* conv2_w   = (const float*)d_in[7];
    const float* gn2_w     = (const float*)d_in[8];
    const float* gn2_b     = (const float*)d_in[9];
    const float* sa_qk_w   = (const float*)d_in[10];
    const float* sa_v_w    = (const float*)d_in[11];
    const float* sa_v_b    = (const float*)d_in[12];
    const float* sa_t_w    = (const float*)d_in[13];
    const float* sa_t_b    = (const float*)d_in[14];
    const float* sa_gn_w   = (const float*)d_in[15];
    const float* sa_gn_b   = (const float*)d_in[16];
    const float* sa_pos_w  = (const float*)d_in[17];
    const float* sa_posG_w = (const float*)d_in[18];
    const float* fuse_w    = (const float*)d_in[19];
    const float* fuse_gn_w = (const float*)d_in[20];
    const float* fuse_gn_b = (const float*)d_in[21];
    const float* convs1_w  = (const float*)d_in[22];
    const float* convs1_b  = (const float*)d_in[23];
    const float* gns1_w    = (const float*)d_in[24];
    const float* gns1_b    = (const float*)d_in[25];
    const float* convs2_w  = (const float*)d_in[26];
    const float* convs2_b  = (const float*)d_in[27];
    const float* gns2_w    = (const float*)d_in[28];
    const float* gns2_b    = (const float*)d_in[29];

    // ---- workspace layout (round-14-proven + 4 small stats buffers) ----
    constexpr long SZ_BN  = (long)BB * 64 * NN;
    constexpr long SZ_BM  = (long)BB * 64 * MM;
    constexpr long SZ_CSP = (long)BB * (NN / 16) * MM;

    float* ws = (float*)d_ws;
    long o = 0;
    float* p_h    = ws + o; o += SZ_BN;
    float* p_hg   = ws + o; o += SZ_BM;
    float* p_q    = ws + o; o += SZ_BN;
    float* p_k    = ws + o; o += SZ_BM;
    float* p_v    = ws + o; o += SZ_BM;
    float* p_u    = ws + o; o += SZ_BN;
    float* p_csp  = ws + o; o += SZ_CSP;
    float* p_cs   = ws + o; o += (long)BB * MM;
    float* p_xc   = ws + o; o += (long)BB * 256 * NN;
    float* p_xf   = ws + o; o += (long)BB * 128 * NN;
    float* p_st   = ws + o; o += 4096;     // generic (t-chain, s2)
    float* p_st_h = ws + o; o += 1024;
    float* p_st_hg= ws + o; o += 1024;
    float* p_st_xf= ws + o; o += 1024;
    float* p_st_s1= ws + o; o += 1024;
    float* p_rmx  = ws + o; o += (long)BB * NN;
    float* p_rin  = ws + o; o += (long)BB * NN;
    float* p_s1   = ws;        // aliases dead SA scratch post-fuse
    float* p_s2   = p_xf;
    ushort* p_qt = (ushort*)p_xf;                      // SA-phase aliases of xf
    ushort* p_kt = (ushort*)(p_xf + 2097152);
    ushort* p_vb = (ushort*)(p_xf + 2097152 + 524288);

    // h = conv1(x) (raw), stats; GN+relu folded into layer-0 q-conv staging
    conv_gemm<<<dim3(NN / 128, 1, BB), 256, 0, stream>>>(
        x, 6, 6L * NN, conv1_w, nullptr, 0, 0, nullptr, nullptr, p_h, 64L * NN, NN);
    gn_stats<<<BB * 16, 256, 0, stream>>>(p_h, 64L * NN, 4, NN, 16, p_st_h);
    // hg = conv2(x_global) (raw), stats; GN+relu folded into k/v conv staging
    conv_mfma<<<dim3(MM / 128, 1, BB), 256, 0, stream>>>(
        x_global, 32, 32L * MM, conv2_w, nullptr, 0, nullptr, nullptr,
        nullptr, nullptr, nullptr, 1, 0, p_hg, 64L * MM, MM, nullptr);
    gn_stats<<<BB * 16, 256, 0, stream>>>(p_hg, 64L * MM, 4, MM, 16, p_st_hg);

    const float* cur = p_h;
    long cur_bs = 64L * NN;
    for (int i = 0; i < 4; ++i) {
        const bool fold0 = (i == 0);   // layer 0: fold GN16(h)+relu into staging
        // q = qk_w*GN(cur) + pos_w*xyz ; bf16-transposed side output -> qt
        conv_mfma<<<dim3(NN / 128, 1, BB), 256, 0, stream>>>(
            cur, fold0 ? 64 : 64, cur_bs, sa_qk_w + i * 4096,
            xyz, 3L * NN, sa_pos_w + i * 192, nullptr,
            fold0 ? gn1_w : nullptr, fold0 ? gn1_b : nullptr,
            fold0 ? p_st_h : nullptr, 4, 1,
            p_q, 64L * NN, NN, p_qt);
        // k = qk_w*GN(hg) + posG_w*xyz_g ; side output -> kt
        conv_mfma<<<dim3(MM / 128, 1, BB), 256, 0, stream>>>(
            p_hg, 64, 64L * MM, sa_qk_w + i * 4096,
            xyz_g, 3L * MM, sa_posG_w + i * 192, nullptr,
            gn2_w, gn2_b, p_st_hg, 4, 1,
            p_k, 64L * MM, MM, p_kt);
        // v = v_w*GN(hg) + posG_w*xyz_g + v_b
        conv_mfma<<<dim3(MM / 128, 1, BB), 256, 0, stream>>>(
            p_hg, 64, 64L * MM, sa_v_w + i * 4096,
            xyz_g, 3L * MM, sa_posG_w + i * 192, sa_v_b + i * 64,
            gn2_w, gn2_b, p_st_hg, 4, 1,
            p_v, 64L * MM, MM, nullptr);
        // phase 0: MFMA softmax stats + column partials
        attn_stats_mfma<<<dim3(NN / 16, BB), 256, 0, stream>>>(p_qt, p_kt, p_rmx, p_rin, p_csp);
        colsum_reduce<<<BB * MM / 256, 256, 0, stream>>>(p_csp, p_cs, NN / 16);
        vscale_cvt<<<BB * 64 * MM / 1024, 256, 0, stream>>>(p_v, p_cs, p_vb);
        // phase 1: u = q - P*v'
        attn_pv_mfma<<<dim3(NN / 32, BB), 256, 0, stream>>>(
            p_qt, p_kt, p_vb, p_rmx, p_rin, p_q, p_u);
        // t = t_w*u + t_b
        conv_mfma<<<dim3(NN / 128, 1, BB), 256, 0, stream>>>(
            p_u, 64, 64L * NN, sa_t_w + i * 4096,
            nullptr, 0, nullptr, sa_t_b + i * 64,
            nullptr, nullptr, nullptr, 1, 0,
            p_h, 64L * NN, NN, nullptr);
        // out_i = q + relu(GN4(t)) -> xc slice i   (residual: keep gn_apply)
        gn_stats<<<BB * 4, 256, 0, stream>>>(p_h, 64L * NN, 16, NN, 4, p_st);
        gn_apply<<<2048, 256, 0, stream>>>(p_h, 64L * NN,
                                           p_xc + (long)i * 64 * NN, 256L * NN,
                                           p_q, 64L * NN,
                                           sa_gn_w + i * 64, sa_gn_b + i * 64, p_st,
                                           64, 16, NN, 1);
        cur = p_xc + (long)i * 64 * NN;
        cur_bs = 256L * NN;
    }

    // xf = fuse_w * xc (raw); GN16+leaky folded into convs1 staging
    conv_mfma<<<dim3(NN / 128, 2, BB), 256, 0, stream>>>(
        p_xc, 256, 256L * NN, fuse_w, nullptr, 0, nullptr, nullptr,
        nullptr, nullptr, nullptr, 1, 0, p_xf, 128L * NN, NN, nullptr);
    gn_stats<<<BB * 16, 256, 0, stream>>>(p_xf, 128L * NN, 8, NN, 16, p_st_xf);
    // s1 = convs1_w * leaky(GN16(xf)) + b (raw); GN8+relu folded into convs2
    conv_mfma<<<dim3(NN / 128, 8, BB), 256, 0, stream>>>(
        p_xf, 128, 128L * NN, convs1_w, nullptr, 0, nullptr, convs1_b,
        fuse_gn_w, fuse_gn_b, p_st_xf, 8, 2, p_s1, 512L * NN, NN, nullptr);
    gn_stats<<<BB * 8, 256, 0, stream>>>(p_s1, 512L * NN, 64, NN, 8, p_st_s1);
    // s2 = convs2_w * relu(GN8(s1)) + b
    conv_mfma<<<dim3(NN / 128, 2, BB), 256, 0, stream>>>(
        p_s1, 512, 512L * NN, convs2_w, nullptr, 0, nullptr, convs2_b,
        gns1_w, gns1_b, p_st_s1, 64, 1, p_s2, 128L * NN, NN, nullptr);
    gn_stats<<<BB * 4, 256, 0, stream>>>(p_s2, 128L * NN, 32, NN, 4, p_st);
    gn_out_transpose<<<dim3(NN / 64, BB), 256, 0, stream>>>(
        p_s2, gns2_w, gns2_b, p_st, (float*)d_out);
}